// Round 1
// baseline (1038.757 us; speedup 1.0000x reference)
//
#include <hip/hip_runtime.h>
#include <math.h>

#define NB 8
#define HH 56
#define WWD 56
#define CC 256
#define PIX (NB*HH*WWD)   // 25088

__device__ __forceinline__ float gelu_exact(float v) {
    return 0.5f * v * (1.0f + erff(v * 0.70710678118654752f));
}

__device__ __forceinline__ void wave_reduce2(float& s, float& sq) {
    #pragma unroll
    for (int o = 32; o >= 1; o >>= 1) {
        s  += __shfl_xor(s, o);
        sq += __shfl_xor(sq, o);
    }
}

// LayerNorm over C=256; one wave per pixel, 4 channels/lane, 4 pixels/block
__global__ __launch_bounds__(256) void ln_kernel(
    const float* __restrict__ in, const float* __restrict__ g,
    const float* __restrict__ b, float* __restrict__ out)
{
    int wave = threadIdx.x >> 6, lane = threadIdx.x & 63;
    int pix = blockIdx.x * 4 + wave;
    int c0 = lane * 4;
    float4 v = *reinterpret_cast<const float4*>(&in[(size_t)pix * CC + c0]);
    float s = v.x + v.y + v.z + v.w;
    float sq = v.x*v.x + v.y*v.y + v.z*v.z + v.w*v.w;
    wave_reduce2(s, sq);
    float mu = s * (1.0f/256.0f);
    float var = sq * (1.0f/256.0f) - mu*mu;
    float rs = rsqrtf(var + 1e-6f);
    float4 gv = *reinterpret_cast<const float4*>(&g[c0]);
    float4 bv = *reinterpret_cast<const float4*>(&b[c0]);
    float4 o;
    o.x = (v.x-mu)*rs*gv.x + bv.x;
    o.y = (v.y-mu)*rs*gv.y + bv.y;
    o.z = (v.z-mu)*rs*gv.z + bv.z;
    o.w = (v.w-mu)*rs*gv.w + bv.w;
    *reinterpret_cast<float4*>(&out[(size_t)pix * CC + c0]) = o;
}

// 3x3 depthwise conv + bias + LN + exact GELU. One wave per pixel.
__global__ __launch_bounds__(256) void dwconv_ln_gelu_kernel(
    const float* __restrict__ xl, const float* __restrict__ w9,
    const float* __restrict__ cb, const float* __restrict__ lg,
    const float* __restrict__ lb, float* __restrict__ out)
{
    int wave = threadIdx.x >> 6, lane = threadIdx.x & 63;
    int pix = blockIdx.x * 4 + wave;
    int n = pix / (HH*WWD); int rem = pix % (HH*WWD);
    int h = rem / WWD, w = rem % WWD;
    int c0 = lane * 4;
    float4 acc = *reinterpret_cast<const float4*>(&cb[c0]);
    #pragma unroll
    for (int t = 0; t < 9; ++t) {
        int hh = h + t/3 - 1, wx = w + t%3 - 1;
        if (hh >= 0 && hh < HH && wx >= 0 && wx < WWD) {
            float4 xv = *reinterpret_cast<const float4*>(
                &xl[(((size_t)n*HH + hh)*WWD + wx)*CC + c0]);
            acc.x += xv.x * w9[(c0+0)*9 + t];
            acc.y += xv.y * w9[(c0+1)*9 + t];
            acc.z += xv.z * w9[(c0+2)*9 + t];
            acc.w += xv.w * w9[(c0+3)*9 + t];
        }
    }
    float s = acc.x+acc.y+acc.z+acc.w;
    float sq = acc.x*acc.x+acc.y*acc.y+acc.z*acc.z+acc.w*acc.w;
    wave_reduce2(s, sq);
    float mu = s*(1.f/256.f), var = sq*(1.f/256.f) - mu*mu;
    float rs = rsqrtf(var + 1e-6f);
    float4 gv = *reinterpret_cast<const float4*>(&lg[c0]);
    float4 bv = *reinterpret_cast<const float4*>(&lb[c0]);
    float4 o;
    o.x = gelu_exact((acc.x-mu)*rs*gv.x + bv.x);
    o.y = gelu_exact((acc.y-mu)*rs*gv.y + bv.y);
    o.z = gelu_exact((acc.z-mu)*rs*gv.z + bv.z);
    o.w = gelu_exact((acc.w-mu)*rs*gv.w + bv.w);
    *reinterpret_cast<float4*>(&out[(size_t)pix * CC + c0]) = o;
}

// Generic tiled fp32 GEMM: C(MxN) = A(MxK) @ B(KxN) + bias, with epilogues.
// EPI 0: plain   EPI 1: gelu   EPI 2: Cout[r] = extra1[r] + extra2[c]*v
#define BM 64
#define BN 64
#define BKK 16
template<int EPI>
__global__ __launch_bounds__(256) void gemm_f32(
    const float* __restrict__ A, const float* __restrict__ B,
    const float* __restrict__ bias, float* __restrict__ Cout,
    int M, int Ncols, int K,
    const float* __restrict__ extra1, const float* __restrict__ extra2,
    int row_off)
{
    __shared__ float As[BKK][BM];
    __shared__ float Bs[BKK][BN + 4];
    int tid = threadIdx.x;
    int tx = tid & 15, ty = tid >> 4;
    int m0 = blockIdx.y * BM;
    int n0 = blockIdx.x * BN;

    float acc[4][4] = {};
    for (int k0 = 0; k0 < K; k0 += BKK) {
        {   // A tile: 64 rows x 16 k, one float4 per thread
            int row = tid >> 2;
            int kq  = (tid & 3) << 2;
            float4 av = *reinterpret_cast<const float4*>(&A[(size_t)(m0+row)*K + k0 + kq]);
            As[kq+0][row] = av.x; As[kq+1][row] = av.y;
            As[kq+2][row] = av.z; As[kq+3][row] = av.w;
        }
        {   // B tile: 16 k x 64 n
            int row = tid >> 4;
            int nq  = (tid & 15) << 2;
            int gn = n0 + nq;
            float4 bv;
            if (gn + 3 < Ncols) {
                bv = *reinterpret_cast<const float4*>(&B[(size_t)(k0+row)*Ncols + gn]);
            } else {
                bv.x = (gn+0 < Ncols) ? B[(size_t)(k0+row)*Ncols + gn+0] : 0.f;
                bv.y = (gn+1 < Ncols) ? B[(size_t)(k0+row)*Ncols + gn+1] : 0.f;
                bv.z = (gn+2 < Ncols) ? B[(size_t)(k0+row)*Ncols + gn+2] : 0.f;
                bv.w = (gn+3 < Ncols) ? B[(size_t)(k0+row)*Ncols + gn+3] : 0.f;
            }
            *reinterpret_cast<float4*>(&Bs[row][nq]) = bv;
        }
        __syncthreads();
        #pragma unroll
        for (int k = 0; k < BKK; ++k) {
            float4 a = *reinterpret_cast<const float4*>(&As[k][ty*4]);
            float4 b = *reinterpret_cast<const float4*>(&Bs[k][tx*4]);
            float av[4] = {a.x,a.y,a.z,a.w};
            float bv[4] = {b.x,b.y,b.z,b.w};
            #pragma unroll
            for (int i = 0; i < 4; ++i)
                #pragma unroll
                for (int j = 0; j < 4; ++j)
                    acc[i][j] += av[i]*bv[j];
        }
        __syncthreads();
    }
    #pragma unroll
    for (int i = 0; i < 4; ++i) {
        int r = m0 + ty*4 + i;
        #pragma unroll
        for (int j = 0; j < 4; ++j) {
            int c = n0 + tx*4 + j;
            if (c < Ncols) {
                float v = acc[i][j] + bias[c];
                if (EPI == 0) {
                    Cout[(size_t)r*Ncols + c] = v;
                } else if (EPI == 1) {
                    Cout[(size_t)r*Ncols + c] = gelu_exact(v);
                } else {
                    size_t gi = (size_t)(row_off + r)*Ncols + c;
                    Cout[gi] = extra1[gi] + extra2[c]*v;
                }
            }
        }
    }
}

// softmax over P=9 per (pixel, group), in place
__global__ __launch_bounds__(256) void softmax9_kernel(float* __restrict__ m, int total)
{
    int i = blockIdx.x*256 + threadIdx.x;
    if (i >= total) return;
    float* p = m + (size_t)i*9;
    float v[9]; float mx = -1e30f;
    #pragma unroll
    for (int j = 0; j < 9; ++j) { v[j] = p[j]; mx = fmaxf(mx, v[j]); }
    float s = 0.f;
    #pragma unroll
    for (int j = 0; j < 9; ++j) { v[j] = expf(v[j]-mx); s += v[j]; }
    float inv = 1.f/s;
    #pragma unroll
    for (int j = 0; j < 9; ++j) p[j] = v[j]*inv;
}

__device__ __forceinline__ float dcn_tap(const float* __restrict__ img, int yi, int xi, float wgt)
{
    // padded coords; real (nonzero) region is [1,56]; everything else contributes 0
    if (yi < 1 || yi > 56 || xi < 1 || xi > 56) return 0.f;
    return wgt * img[((size_t)(yi-1)*WWD + (xi-1)) * CC];
}

// Deformable sampling + mask aggregation. One block per pixel; thread = (g, c).
__global__ __launch_bounds__(256) void dcn_sample_kernel(
    const float* __restrict__ xproj, const float* __restrict__ offs,
    const float* __restrict__ msk, float* __restrict__ dcn)
{
    int pix = blockIdx.x;
    int n = pix / (HH*WWD); int rem = pix % (HH*WWD);
    int h = rem / WWD, w = rem % WWD;
    int g = threadIdx.x >> 4, c = threadIdx.x & 15;
    const float* op = offs + (size_t)pix*288 + g*18;
    const float* mp = msk + (size_t)pix*144 + g*9;
    const float* img = xproj + (size_t)n*(HH*WWD*CC) + g*16 + c;
    float acc = 0.f;
    #pragma unroll
    for (int p = 0; p < 9; ++p) {
        float ox = op[p*2+0], oy = op[p*2+1];
        // padded-image coords: x = w+1 + (p/3 - 1) + ox
        float xs = (float)(w + p/3) + ox;
        float ys = (float)(h + p%3) + oy;
        float x0f = floorf(xs), y0f = floorf(ys);
        float lx = xs - x0f, ly = ys - y0f;
        int x0 = (int)x0f, y0 = (int)y0f;
        float s;
        s  = dcn_tap(img, y0,   x0,   (1.f-lx)*(1.f-ly));
        s += dcn_tap(img, y0,   x0+1, lx*(1.f-ly));
        s += dcn_tap(img, y0+1, x0,   (1.f-lx)*ly);
        s += dcn_tap(img, y0+1, x0+1, lx*ly);
        acc += mp[p] * s;
    }
    dcn[(size_t)pix*CC + g*16 + c] = acc;
}

extern "C" void kernel_launch(void* const* d_in, const int* in_sizes, int n_in,
                              void* d_out, int out_size, void* d_ws, size_t ws_size,
                              hipStream_t stream)
{
    const float* x    = (const float*)d_in[0];
    const float* n1g  = (const float*)d_in[1];
    const float* n1b  = (const float*)d_in[2];
    const float* n2g  = (const float*)d_in[3];
    const float* n2b  = (const float*)d_in[4];
    const float* g1   = (const float*)d_in[5];
    const float* g2   = (const float*)d_in[6];
    const float* dww  = (const float*)d_in[7];
    const float* dwb  = (const float*)d_in[8];
    const float* dlng = (const float*)d_in[9];
    const float* dlnb = (const float*)d_in[10];
    const float* offw = (const float*)d_in[11];
    const float* offb = (const float*)d_in[12];
    const float* mskw = (const float*)d_in[13];
    const float* mskb = (const float*)d_in[14];
    const float* inw  = (const float*)d_in[15];
    const float* inb  = (const float*)d_in[16];
    const float* outw = (const float*)d_in[17];
    const float* outb = (const float*)d_in[18];
    const float* f1w  = (const float*)d_in[19];
    const float* f1b  = (const float*)d_in[20];
    const float* f2w  = (const float*)d_in[21];
    const float* f2b  = (const float*)d_in[22];
    float* out = (float*)d_out;

    const size_t PC = (size_t)PIX * CC;          // 6,422,528
    float* ws    = (float*)d_ws;
    float* xl    = ws;                            // region A: xl -> dcn -> y2
    float* xproj = ws + PC;                       // region B: xproj -> fc1 panel
    float* x1    = ws + 2*PC;                     // region C: x1 -> xres
    float* offs  = ws + 3*PC;                     // 25088*288
    float* msk   = ws + 3*PC + (size_t)PIX*288;   // 25088*144
    float* dcn   = xl;
    float* xres  = x1;
    float* y2    = xl;
    float* f1p   = xproj;                         // 6272*1024 == PC

    // 1. LN1
    ln_kernel<<<PIX/4, 256, 0, stream>>>(x, n1g, n1b, xl);
    // 2. in_proj -> xproj
    gemm_f32<0><<<dim3(4, PIX/64), 256, 0, stream>>>(xl, inw, inb, xproj,
        PIX, 256, 256, nullptr, nullptr, 0);
    // 3. depthwise conv + LN + GELU -> x1
    dwconv_ln_gelu_kernel<<<PIX/4, 256, 0, stream>>>(xl, dww, dwb, dlng, dlnb, x1);
    // 4. offset & mask GEMMs
    gemm_f32<0><<<dim3(5, PIX/64), 256, 0, stream>>>(x1, offw, offb, offs,
        PIX, 288, 256, nullptr, nullptr, 0);
    gemm_f32<0><<<dim3(3, PIX/64), 256, 0, stream>>>(x1, mskw, mskb, msk,
        PIX, 144, 256, nullptr, nullptr, 0);
    // 5. softmax over P
    softmax9_kernel<<<(PIX*16)/256, 256, 0, stream>>>(msk, PIX*16);
    // 6. deformable sampling -> dcn (reuses xl region)
    dcn_sample_kernel<<<PIX, 256, 0, stream>>>(xproj, offs, msk, dcn);
    // 7. out_proj + residual: xres = x + gamma1*(dcn@out_w + out_b)
    gemm_f32<2><<<dim3(4, PIX/64), 256, 0, stream>>>(dcn, outw, outb, xres,
        PIX, 256, 256, x, g1, 0);
    // 8. LN2 -> y2 (reuses region A)
    ln_kernel<<<PIX/4, 256, 0, stream>>>(xres, n2g, n2b, y2);
    // 9. MLP in 4 row panels: fc1+gelu -> f1p ; fc2 + residual -> out
    const int PM = PIX/4;  // 6272 rows per panel
    for (int pnl = 0; pnl < 4; ++pnl) {
        gemm_f32<1><<<dim3(16, PM/64), 256, 0, stream>>>(
            y2 + (size_t)pnl*PM*CC, f1w, f1b, f1p, PM, 1024, 256, nullptr, nullptr, 0);
        gemm_f32<2><<<dim3(4, PM/64), 256, 0, stream>>>(
            f1p, f2w, f2b, out, PM, 256, 1024, xres, g2, pnl*PM);
    }
}

// Round 2
// 428.572 us; speedup vs baseline: 2.4238x; 2.4238x over previous
//
#include <hip/hip_runtime.h>
#include <math.h>

#define NB 8
#define HH 56
#define WWD 56
#define CC 256
#define PIX (NB*HH*WWD)   // 25088

typedef __attribute__((ext_vector_type(8))) short bf16x8;
typedef __attribute__((ext_vector_type(4))) float f32x4;

__device__ __forceinline__ float gelu_exact(float v) {
    return 0.5f * v * (1.0f + erff(v * 0.70710678118654752f));
}
__device__ __forceinline__ unsigned short f2bf(float f) {
    unsigned u = __float_as_uint(f);
    unsigned r = (u + 0x7fffu + ((u >> 16) & 1u)) >> 16;
    return (unsigned short)r;
}
__device__ __forceinline__ float bf2f(unsigned short b) {
    return __uint_as_float(((unsigned)b) << 16);
}
__device__ __forceinline__ void gl_lds16(const void* g, void* l) {
    __builtin_amdgcn_global_load_lds(
        (const __attribute__((address_space(1))) void*)g,
        (__attribute__((address_space(3))) void*)l, 16, 0, 0);
}
__device__ __forceinline__ void wave_reduce2(float& s, float& sq) {
    #pragma unroll
    for (int o = 32; o >= 1; o >>= 1) {
        s  += __shfl_xor(s, o);
        sq += __shfl_xor(sq, o);
    }
}

// fp32 -> bf16 transposed weight: Bt[n*K + k] = W[k*N + n] (zero pad rows n>=N)
__global__ __launch_bounds__(256) void wtrans_kernel(
    const float* __restrict__ W, unsigned short* __restrict__ Bt,
    int K, int N, int Npad)
{
    int i = blockIdx.x * 256 + threadIdx.x;
    if (i >= Npad * K) return;
    int n = i / K, k = i - n * K;
    float v = (n < N) ? W[(size_t)k * N + n] : 0.f;
    Bt[i] = f2bf(v);
}

// LayerNorm over C=256, fp32 in -> bf16 out. One wave/pixel.
__global__ __launch_bounds__(256) void ln_bf_kernel(
    const float* __restrict__ in, const float* __restrict__ g,
    const float* __restrict__ b, unsigned short* __restrict__ out)
{
    int wave = threadIdx.x >> 6, lane = threadIdx.x & 63;
    int pix = blockIdx.x * 4 + wave;
    int c0 = lane * 4;
    float4 v = *reinterpret_cast<const float4*>(&in[(size_t)pix * CC + c0]);
    float s = v.x + v.y + v.z + v.w;
    float sq = v.x*v.x + v.y*v.y + v.z*v.z + v.w*v.w;
    wave_reduce2(s, sq);
    float mu = s * (1.0f/256.0f);
    float var = sq * (1.0f/256.0f) - mu*mu;
    float rs = rsqrtf(var + 1e-6f);
    float4 gv = *reinterpret_cast<const float4*>(&g[c0]);
    float4 bv = *reinterpret_cast<const float4*>(&b[c0]);
    ushort4 o;
    o.x = f2bf((v.x-mu)*rs*gv.x + bv.x);
    o.y = f2bf((v.y-mu)*rs*gv.y + bv.y);
    o.z = f2bf((v.z-mu)*rs*gv.z + bv.z);
    o.w = f2bf((v.w-mu)*rs*gv.w + bv.w);
    *reinterpret_cast<ushort4*>(&out[(size_t)pix * CC + c0]) = o;
}

// 3x3 depthwise conv (bf16 in) + bias + LN + exact GELU -> bf16 out.
__global__ __launch_bounds__(256) void dwconv_ln_gelu_kernel(
    const unsigned short* __restrict__ xl, const float* __restrict__ w9,
    const float* __restrict__ cb, const float* __restrict__ lg,
    const float* __restrict__ lb, unsigned short* __restrict__ out)
{
    int wave = threadIdx.x >> 6, lane = threadIdx.x & 63;
    int pix = blockIdx.x * 4 + wave;
    int n = pix / (HH*WWD); int rem = pix % (HH*WWD);
    int h = rem / WWD, w = rem % WWD;
    int c0 = lane * 4;
    float a0 = cb[c0+0], a1 = cb[c0+1], a2 = cb[c0+2], a3 = cb[c0+3];
    #pragma unroll
    for (int t = 0; t < 9; ++t) {
        int hh = h + t/3 - 1, wx = w + t%3 - 1;
        if (hh >= 0 && hh < HH && wx >= 0 && wx < WWD) {
            ushort4 xv = *reinterpret_cast<const ushort4*>(
                &xl[(((size_t)n*HH + hh)*WWD + wx)*CC + c0]);
            a0 += bf2f(xv.x) * w9[(c0+0)*9 + t];
            a1 += bf2f(xv.y) * w9[(c0+1)*9 + t];
            a2 += bf2f(xv.z) * w9[(c0+2)*9 + t];
            a3 += bf2f(xv.w) * w9[(c0+3)*9 + t];
        }
    }
    float s = a0+a1+a2+a3;
    float sq = a0*a0+a1*a1+a2*a2+a3*a3;
    wave_reduce2(s, sq);
    float mu = s*(1.f/256.f), var = sq*(1.f/256.f) - mu*mu;
    float rs = rsqrtf(var + 1e-6f);
    ushort4 o;
    o.x = f2bf(gelu_exact((a0-mu)*rs*lg[c0+0] + lb[c0+0]));
    o.y = f2bf(gelu_exact((a1-mu)*rs*lg[c0+1] + lb[c0+1]));
    o.z = f2bf(gelu_exact((a2-mu)*rs*lg[c0+2] + lb[c0+2]));
    o.w = f2bf(gelu_exact((a3-mu)*rs*lg[c0+3] + lb[c0+3]));
    *reinterpret_cast<ushort4*>(&out[(size_t)pix * CC + c0]) = o;
}

// ---------------- bf16 MFMA GEMM ----------------
// C(MxN) = A(MxK,bf16) @ Bt(NpadxK,bf16)^T + bias.
// 128x128 tile, BK=32, 4 waves (2x2 of 64x64), mfma_f32_16x16x32_bf16.
// EPI 0: fp32 out.  EPI 1: bf16 out with gelu.  EPI 2: fp32 out = extra1 + extra2[c]*v.
template<int EPI>
__global__ __launch_bounds__(256) void gemm_bf16(
    const unsigned short* __restrict__ A, const unsigned short* __restrict__ Bt,
    const float* __restrict__ bias, float* __restrict__ Cf,
    unsigned short* __restrict__ Cb, int M, int N, int K,
    const float* __restrict__ extra1, const float* __restrict__ extra2)
{
    __shared__ unsigned short Al[4096];   // [kb:4][row:128][j:8]
    __shared__ unsigned short Bl[4096];
    const int tid = threadIdx.x;
    const int wave = tid >> 6, lane = tid & 63;
    const int wr = wave >> 1, wc = wave & 1;
    const int lm = lane & 15, kq = lane >> 4;
    const int m0 = blockIdx.y * 128, n0 = blockIdx.x * 128;

    f32x4 acc[4][4];
    #pragma unroll
    for (int i = 0; i < 4; ++i)
        #pragma unroll
        for (int j = 0; j < 4; ++j)
            acc[i][j] = (f32x4){0.f, 0.f, 0.f, 0.f};

    const int arow = wr*64 + lm;
    const int brow = wc*64 + lm;

    for (int k0 = 0; k0 < K; k0 += 32) {
        #pragma unroll
        for (int is = 0; is < 2; ++is) {
            int idx = is*256 + tid;
            int kbi = idx >> 7, row = idx & 127;
            int ldsoff = (is*4 + wave) * 1024;   // bytes, wave-uniform
            gl_lds16(A  + (size_t)(m0+row)*K + k0 + kbi*8, (char*)Al + ldsoff);
            gl_lds16(Bt + (size_t)(n0+row)*K + k0 + kbi*8, (char*)Bl + ldsoff);
        }
        __syncthreads();
        bf16x8 af[4], bv[4];
        #pragma unroll
        for (int mi = 0; mi < 4; ++mi)
            af[mi] = *reinterpret_cast<const bf16x8*>(&Al[(kq*128 + arow + mi*16)*8]);
        #pragma unroll
        for (int ni = 0; ni < 4; ++ni)
            bv[ni] = *reinterpret_cast<const bf16x8*>(&Bl[(kq*128 + brow + ni*16)*8]);
        #pragma unroll
        for (int mi = 0; mi < 4; ++mi)
            #pragma unroll
            for (int ni = 0; ni < 4; ++ni)
                acc[mi][ni] = __builtin_amdgcn_mfma_f32_16x16x32_bf16(
                    af[mi], bv[ni], acc[mi][ni], 0, 0, 0);
        __syncthreads();
    }

    #pragma unroll
    for (int mi = 0; mi < 4; ++mi) {
        #pragma unroll
        for (int ni = 0; ni < 4; ++ni) {
            int c = n0 + wc*64 + ni*16 + lm;
            if (c < N) {
                float bb = bias[c];
                #pragma unroll
                for (int j = 0; j < 4; ++j) {
                    int r = m0 + wr*64 + mi*16 + kq*4 + j;
                    float v = acc[mi][ni][j] + bb;
                    if (EPI == 0) {
                        Cf[(size_t)r*N + c] = v;
                    } else if (EPI == 1) {
                        Cb[(size_t)r*N + c] = f2bf(gelu_exact(v));
                    } else {
                        size_t gi = (size_t)r*N + c;
                        Cf[gi] = extra1[gi] + extra2[c]*v;
                    }
                }
            }
        }
    }
}

// softmax over P=9 per (pixel, group), in place (fp32)
__global__ __launch_bounds__(256) void softmax9_kernel(float* __restrict__ m, int total)
{
    int i = blockIdx.x*256 + threadIdx.x;
    if (i >= total) return;
    float* p = m + (size_t)i*9;
    float v[9]; float mx = -1e30f;
    #pragma unroll
    for (int j = 0; j < 9; ++j) { v[j] = p[j]; mx = fmaxf(mx, v[j]); }
    float s = 0.f;
    #pragma unroll
    for (int j = 0; j < 9; ++j) { v[j] = expf(v[j]-mx); s += v[j]; }
    float inv = 1.f/s;
    #pragma unroll
    for (int j = 0; j < 9; ++j) p[j] = v[j]*inv;
}

__device__ __forceinline__ void tap4(const float* __restrict__ img, int yi, int xi,
                                     float wgt, float4& s) {
    // padded coords; nonzero region is [1,56]
    if (yi >= 1 && yi <= 56 && xi >= 1 && xi <= 56) {
        float4 v = *reinterpret_cast<const float4*>(
            &img[(((size_t)(yi-1))*WWD + (xi-1)) * CC]);
        s.x += wgt*v.x; s.y += wgt*v.y; s.z += wgt*v.z; s.w += wgt*v.w;
    }
}

// Deformable sampling + mask aggregation. 1 wave/pixel; lane = (g, c4); float4 channels.
__global__ __launch_bounds__(256) void dcn_sample_kernel(
    const float* __restrict__ xproj, const float* __restrict__ offs,
    const float* __restrict__ msk, unsigned short* __restrict__ dcn)
{
    int wave = threadIdx.x >> 6, lane = threadIdx.x & 63;
    int pix = blockIdx.x * 4 + wave;
    int n = pix / (HH*WWD); int rem = pix % (HH*WWD);
    int h = rem / WWD, w = rem % WWD;
    int g = lane >> 2, c4 = lane & 3;
    const float* op = offs + (size_t)pix*288 + g*18;
    const float* mp = msk + (size_t)pix*144 + g*9;
    const float* img = xproj + (size_t)n*(HH*WWD*CC) + g*16 + c4*4;
    float4 acc = {0.f, 0.f, 0.f, 0.f};
    #pragma unroll
    for (int p = 0; p < 9; ++p) {
        float ox = op[p*2+0], oy = op[p*2+1];
        float xs = (float)(w + p/3) + ox;   // padded-image coords
        float ys = (float)(h + p%3) + oy;
        float x0f = floorf(xs), y0f = floorf(ys);
        float lx = xs - x0f, ly = ys - y0f;
        int x0 = (int)x0f, y0 = (int)y0f;
        float4 s = {0.f, 0.f, 0.f, 0.f};
        tap4(img, y0,   x0,   (1.f-lx)*(1.f-ly), s);
        tap4(img, y0,   x0+1, lx*(1.f-ly),       s);
        tap4(img, y0+1, x0,   (1.f-lx)*ly,       s);
        tap4(img, y0+1, x0+1, lx*ly,             s);
        float m = mp[p];
        acc.x += m*s.x; acc.y += m*s.y; acc.z += m*s.z; acc.w += m*s.w;
    }
    ushort4 o;
    o.x = f2bf(acc.x); o.y = f2bf(acc.y); o.z = f2bf(acc.z); o.w = f2bf(acc.w);
    *reinterpret_cast<ushort4*>(&dcn[(size_t)pix*CC + g*16 + c4*4]) = o;
}

extern "C" void kernel_launch(void* const* d_in, const int* in_sizes, int n_in,
                              void* d_out, int out_size, void* d_ws, size_t ws_size,
                              hipStream_t stream)
{
    const float* x    = (const float*)d_in[0];
    const float* n1g  = (const float*)d_in[1];
    const float* n1b  = (const float*)d_in[2];
    const float* n2g  = (const float*)d_in[3];
    const float* n2b  = (const float*)d_in[4];
    const float* g1   = (const float*)d_in[5];
    const float* g2   = (const float*)d_in[6];
    const float* dww  = (const float*)d_in[7];
    const float* dwb  = (const float*)d_in[8];
    const float* dlng = (const float*)d_in[9];
    const float* dlnb = (const float*)d_in[10];
    const float* offw = (const float*)d_in[11];
    const float* offb = (const float*)d_in[12];
    const float* mskw = (const float*)d_in[13];
    const float* mskb = (const float*)d_in[14];
    const float* inw  = (const float*)d_in[15];
    const float* inb  = (const float*)d_in[16];
    const float* outw = (const float*)d_in[17];
    const float* outb = (const float*)d_in[18];
    const float* f1w  = (const float*)d_in[19];
    const float* f1b  = (const float*)d_in[20];
    const float* f2w  = (const float*)d_in[21];
    const float* f2b  = (const float*)d_in[22];
    float* out = (float*)d_out;

    char* base = (char*)d_ws;
    // arena (bytes)
    unsigned short* xl_bf  = (unsigned short*)(base + 0);            // 12,845,056 B
    float*          xproj  = (float*)(base + 12845056);              // 25,690,112 B
    unsigned short* x1_bf  = (unsigned short*)(base + 38535168);     // 12,845,056 B
    float*          offs   = (float*)(base + 51380224);              // 28,901,376 B
    float*          msk    = (float*)(base + 80281600);              // 14,450,688 B
    unsigned short* dcn_bf = xl_bf;                                   // reuse
    float*          xres   = xproj;                                   // reuse
    unsigned short* y2_bf  = x1_bf;                                   // reuse
    unsigned short* h1     = (unsigned short*)(base + 51380224);     // 51,380,224 B (over offs+msk)
    unsigned short* btb    = (unsigned short*)(base + 102760448);    // 1,638,400 B
    unsigned short* bt_in  = btb + 0;
    unsigned short* bt_off = btb + 65536;
    unsigned short* bt_msk = btb + 163840;
    unsigned short* bt_out = btb + 229376;
    unsigned short* bt_fc1 = btb + 294912;
    unsigned short* bt_fc2 = btb + 557056;

    // 0. weight transposes (fp32 -> bf16, N-major, padded to x128 rows)
    wtrans_kernel<<<256,  256, 0, stream>>>(inw,  bt_in,  256, 256,  256);
    wtrans_kernel<<<384,  256, 0, stream>>>(offw, bt_off, 256, 288,  384);
    wtrans_kernel<<<256,  256, 0, stream>>>(mskw, bt_msk, 256, 144,  256);
    wtrans_kernel<<<256,  256, 0, stream>>>(outw, bt_out, 256, 256,  256);
    wtrans_kernel<<<1024, 256, 0, stream>>>(f1w,  bt_fc1, 256, 1024, 1024);
    wtrans_kernel<<<1024, 256, 0, stream>>>(f2w,  bt_fc2, 1024, 256, 256);

    // 1. LN1 -> xl (bf16)
    ln_bf_kernel<<<PIX/4, 256, 0, stream>>>(x, n1g, n1b, xl_bf);
    // 2. in_proj -> xproj (fp32)
    gemm_bf16<0><<<dim3(2,196), 256, 0, stream>>>(xl_bf, bt_in, inb, xproj,
        nullptr, PIX, 256, 256, nullptr, nullptr);
    // 3. depthwise conv + LN + GELU -> x1 (bf16)
    dwconv_ln_gelu_kernel<<<PIX/4, 256, 0, stream>>>(xl_bf, dww, dwb, dlng, dlnb, x1_bf);
    // 4. offset & mask GEMMs (fp32 out)
    gemm_bf16<0><<<dim3(3,196), 256, 0, stream>>>(x1_bf, bt_off, offb, offs,
        nullptr, PIX, 288, 256, nullptr, nullptr);
    gemm_bf16<0><<<dim3(2,196), 256, 0, stream>>>(x1_bf, bt_msk, mskb, msk,
        nullptr, PIX, 144, 256, nullptr, nullptr);
    // 5. softmax over P
    softmax9_kernel<<<(PIX*16)/256, 256, 0, stream>>>(msk, PIX*16);
    // 6. deformable sampling -> dcn (bf16, reuses xl region)
    dcn_sample_kernel<<<PIX/4, 256, 0, stream>>>(xproj, offs, msk, dcn_bf);
    // 7. out_proj + residual: xres = x + gamma1*(dcn@out_w + out_b)  (fp32, reuses xproj region)
    gemm_bf16<2><<<dim3(2,196), 256, 0, stream>>>(dcn_bf, bt_out, outb, xres,
        nullptr, PIX, 256, 256, x, g1);
    // 8. LN2 -> y2 (bf16, reuses x1 region)
    ln_bf_kernel<<<PIX/4, 256, 0, stream>>>(xres, n2g, n2b, y2_bf);
    // 9. fc1 + gelu -> h1 (bf16)
    gemm_bf16<1><<<dim3(8,196), 256, 0, stream>>>(y2_bf, bt_fc1, f1b, nullptr,
        h1, PIX, 1024, 256, nullptr, nullptr);
    // 10. fc2 + residual -> out (fp32)
    gemm_bf16<2><<<dim3(2,196), 256, 0, stream>>>(h1, bt_fc2, f2b, out,
        nullptr, PIX, 256, 1024, xres, g2);
}

// Round 3
// 349.504 us; speedup vs baseline: 2.9721x; 1.2262x over previous
//
#include <hip/hip_runtime.h>
#include <math.h>

#define NB 8
#define HH 56
#define WWD 56
#define CC 256
#define PIX (NB*HH*WWD)   // 25088

typedef __attribute__((ext_vector_type(8))) short bf16x8;
typedef __attribute__((ext_vector_type(4))) float f32x4;

__device__ __forceinline__ float gelu_exact(float v) {
    return 0.5f * v * (1.0f + erff(v * 0.70710678118654752f));
}
__device__ __forceinline__ unsigned short f2bf(float f) {
    unsigned u = __float_as_uint(f);
    unsigned r = (u + 0x7fffu + ((u >> 16) & 1u)) >> 16;
    return (unsigned short)r;
}
__device__ __forceinline__ float bf2f(unsigned short b) {
    return __uint_as_float(((unsigned)b) << 16);
}
__device__ __forceinline__ void gl_lds16(const void* g, void* l) {
    __builtin_amdgcn_global_load_lds(
        (const __attribute__((address_space(1))) void*)g,
        (__attribute__((address_space(3))) void*)l, 16, 0, 0);
}
__device__ __forceinline__ void wave_reduce2(float& s, float& sq) {
    #pragma unroll
    for (int o = 32; o >= 1; o >>= 1) {
        s  += __shfl_xor(s, o);
        sq += __shfl_xor(sq, o);
    }
}

// fp32 -> bf16 transposed weight: Bt[n*K + k] = W[k*N + n] (zero pad rows n>=N)
__global__ __launch_bounds__(256) void wtrans_kernel(
    const float* __restrict__ W, unsigned short* __restrict__ Bt,
    int K, int N, int Npad)
{
    int i = blockIdx.x * 256 + threadIdx.x;
    if (i >= Npad * K) return;
    int n = i / K, k = i - n * K;
    float v = (n < N) ? W[(size_t)k * N + n] : 0.f;
    Bt[i] = f2bf(v);
}

// LayerNorm over C=256, fp32 in -> bf16 out. One wave/pixel.
__global__ __launch_bounds__(256) void ln_bf_kernel(
    const float* __restrict__ in, const float* __restrict__ g,
    const float* __restrict__ b, unsigned short* __restrict__ out)
{
    int wave = threadIdx.x >> 6, lane = threadIdx.x & 63;
    int pix = blockIdx.x * 4 + wave;
    int c0 = lane * 4;
    float4 v = *reinterpret_cast<const float4*>(&in[(size_t)pix * CC + c0]);
    float s = v.x + v.y + v.z + v.w;
    float sq = v.x*v.x + v.y*v.y + v.z*v.z + v.w*v.w;
    wave_reduce2(s, sq);
    float mu = s * (1.0f/256.0f);
    float var = sq * (1.0f/256.0f) - mu*mu;
    float rs = rsqrtf(var + 1e-6f);
    float4 gv = *reinterpret_cast<const float4*>(&g[c0]);
    float4 bv = *reinterpret_cast<const float4*>(&b[c0]);
    ushort4 o;
    o.x = f2bf((v.x-mu)*rs*gv.x + bv.x);
    o.y = f2bf((v.y-mu)*rs*gv.y + bv.y);
    o.z = f2bf((v.z-mu)*rs*gv.z + bv.z);
    o.w = f2bf((v.w-mu)*rs*gv.w + bv.w);
    *reinterpret_cast<ushort4*>(&out[(size_t)pix * CC + c0]) = o;
}

// 3x3 depthwise conv (bf16 in) + bias + LN + exact GELU -> bf16 out.
// XCD-chunked block remap for neighborhood L2 locality.
__global__ __launch_bounds__(256) void dwconv_ln_gelu_kernel(
    const unsigned short* __restrict__ xl, const float* __restrict__ w9,
    const float* __restrict__ cb, const float* __restrict__ lg,
    const float* __restrict__ lb, unsigned short* __restrict__ out)
{
    int bid = blockIdx.x;
    int wg = (bid & 7) * (gridDim.x >> 3) + (bid >> 3);
    int wave = threadIdx.x >> 6, lane = threadIdx.x & 63;
    int pix = wg * 4 + wave;
    int n = pix / (HH*WWD); int rem = pix % (HH*WWD);
    int h = rem / WWD, w = rem % WWD;
    int c0 = lane * 4;
    float a0 = cb[c0+0], a1 = cb[c0+1], a2 = cb[c0+2], a3 = cb[c0+3];
    #pragma unroll
    for (int t = 0; t < 9; ++t) {
        int hh = h + t/3 - 1, wx = w + t%3 - 1;
        if (hh >= 0 && hh < HH && wx >= 0 && wx < WWD) {
            ushort4 xv = *reinterpret_cast<const ushort4*>(
                &xl[(((size_t)n*HH + hh)*WWD + wx)*CC + c0]);
            a0 += bf2f(xv.x) * w9[(c0+0)*9 + t];
            a1 += bf2f(xv.y) * w9[(c0+1)*9 + t];
            a2 += bf2f(xv.z) * w9[(c0+2)*9 + t];
            a3 += bf2f(xv.w) * w9[(c0+3)*9 + t];
        }
    }
    float s = a0+a1+a2+a3;
    float sq = a0*a0+a1*a1+a2*a2+a3*a3;
    wave_reduce2(s, sq);
    float mu = s*(1.f/256.f), var = sq*(1.f/256.f) - mu*mu;
    float rs = rsqrtf(var + 1e-6f);
    ushort4 o;
    o.x = f2bf(gelu_exact((a0-mu)*rs*lg[c0+0] + lb[c0+0]));
    o.y = f2bf(gelu_exact((a1-mu)*rs*lg[c0+1] + lb[c0+1]));
    o.z = f2bf(gelu_exact((a2-mu)*rs*lg[c0+2] + lb[c0+2]));
    o.w = f2bf(gelu_exact((a3-mu)*rs*lg[c0+3] + lb[c0+3]));
    *reinterpret_cast<ushort4*>(&out[(size_t)pix * CC + c0]) = o;
}

// ---------------- bf16 MFMA GEMM ----------------
// C(MxN) = A(MxK,bf16) @ Bt(NpadxK,bf16)^T + bias.
// 128x128 tile, BK=32, 4 waves (2x2 of 64x64), mfma_f32_16x16x32_bf16.
// EPI 0: fp32 out. EPI 1: bf16 gelu. EPI 2: fp32 extra1+extra2[c]*v. EPI 3: bf16 plain.
template<int EPI>
__global__ __launch_bounds__(256) void gemm_bf16(
    const unsigned short* __restrict__ A, const unsigned short* __restrict__ Bt,
    const float* __restrict__ bias, float* __restrict__ Cf,
    unsigned short* __restrict__ Cb, int M, int N, int K,
    const float* __restrict__ extra1, const float* __restrict__ extra2)
{
    __shared__ unsigned short Al[4096];   // [kb:4][row:128][j:8]
    __shared__ unsigned short Bl[4096];
    const int tid = threadIdx.x;
    const int wave = tid >> 6, lane = tid & 63;
    const int wr = wave >> 1, wc = wave & 1;
    const int lm = lane & 15, kq = lane >> 4;
    const int m0 = blockIdx.y * 128, n0 = blockIdx.x * 128;

    f32x4 acc[4][4];
    #pragma unroll
    for (int i = 0; i < 4; ++i)
        #pragma unroll
        for (int j = 0; j < 4; ++j)
            acc[i][j] = (f32x4){0.f, 0.f, 0.f, 0.f};

    const int arow = wr*64 + lm;
    const int brow = wc*64 + lm;

    for (int k0 = 0; k0 < K; k0 += 32) {
        #pragma unroll
        for (int is = 0; is < 2; ++is) {
            int idx = is*256 + tid;
            int kbi = idx >> 7, row = idx & 127;
            int ldsoff = (is*4 + wave) * 1024;   // bytes, wave-uniform
            gl_lds16(A  + (size_t)(m0+row)*K + k0 + kbi*8, (char*)Al + ldsoff);
            gl_lds16(Bt + (size_t)(n0+row)*K + k0 + kbi*8, (char*)Bl + ldsoff);
        }
        __syncthreads();
        bf16x8 af[4], bv[4];
        #pragma unroll
        for (int mi = 0; mi < 4; ++mi)
            af[mi] = *reinterpret_cast<const bf16x8*>(&Al[(kq*128 + arow + mi*16)*8]);
        #pragma unroll
        for (int ni = 0; ni < 4; ++ni)
            bv[ni] = *reinterpret_cast<const bf16x8*>(&Bl[(kq*128 + brow + ni*16)*8]);
        #pragma unroll
        for (int mi = 0; mi < 4; ++mi)
            #pragma unroll
            for (int ni = 0; ni < 4; ++ni)
                acc[mi][ni] = __builtin_amdgcn_mfma_f32_16x16x32_bf16(
                    af[mi], bv[ni], acc[mi][ni], 0, 0, 0);
        __syncthreads();
    }

    #pragma unroll
    for (int mi = 0; mi < 4; ++mi) {
        #pragma unroll
        for (int ni = 0; ni < 4; ++ni) {
            int c = n0 + wc*64 + ni*16 + lm;
            if (c < N) {
                float bb = bias[c];
                #pragma unroll
                for (int j = 0; j < 4; ++j) {
                    int r = m0 + wr*64 + mi*16 + kq*4 + j;
                    float v = acc[mi][ni][j] + bb;
                    if (EPI == 0) {
                        Cf[(size_t)r*N + c] = v;
                    } else if (EPI == 1) {
                        Cb[(size_t)r*N + c] = f2bf(gelu_exact(v));
                    } else if (EPI == 2) {
                        size_t gi = (size_t)r*N + c;
                        Cf[gi] = extra1[gi] + extra2[c]*v;
                    } else {
                        Cb[(size_t)r*N + c] = f2bf(v);
                    }
                }
            }
        }
    }
}

// softmax over P=9 per (pixel, group), in place (fp32)
__global__ __launch_bounds__(256) void softmax9_kernel(float* __restrict__ m, int total)
{
    int i = blockIdx.x*256 + threadIdx.x;
    if (i >= total) return;
    float* p = m + (size_t)i*9;
    float v[9]; float mx = -1e30f;
    #pragma unroll
    for (int j = 0; j < 9; ++j) { v[j] = p[j]; mx = fmaxf(mx, v[j]); }
    float s = 0.f;
    #pragma unroll
    for (int j = 0; j < 9; ++j) { v[j] = expf(v[j]-mx); s += v[j]; }
    float inv = 1.f/s;
    #pragma unroll
    for (int j = 0; j < 9; ++j) p[j] = v[j]*inv;
}

__device__ __forceinline__ void tap4b(const unsigned short* __restrict__ img, int yi, int xi,
                                      float wgt, float4& s) {
    // padded coords; nonzero region is [1,56]
    if (yi >= 1 && yi <= 56 && xi >= 1 && xi <= 56) {
        ushort4 v = *reinterpret_cast<const ushort4*>(
            &img[(((size_t)(yi-1))*WWD + (xi-1)) * CC]);
        s.x += wgt*bf2f(v.x); s.y += wgt*bf2f(v.y);
        s.z += wgt*bf2f(v.z); s.w += wgt*bf2f(v.w);
    }
}

// Deformable sampling + mask aggregation. 1 wave/pixel; lane = (g, c4).
// bf16 image; XCD-chunked block remap (one batch image per XCD -> L2-resident slice).
__global__ __launch_bounds__(256) void dcn_sample_kernel(
    const unsigned short* __restrict__ xproj, const float* __restrict__ offs,
    const float* __restrict__ msk, unsigned short* __restrict__ dcn)
{
    int bid = blockIdx.x;
    int wg = (bid & 7) * (gridDim.x >> 3) + (bid >> 3);
    int wave = threadIdx.x >> 6, lane = threadIdx.x & 63;
    int pix = wg * 4 + wave;
    int n = pix / (HH*WWD); int rem = pix % (HH*WWD);
    int h = rem / WWD, w = rem % WWD;
    int g = lane >> 2, c4 = lane & 3;
    const float* op = offs + (size_t)pix*288 + g*18;
    const float* mp = msk + (size_t)pix*144 + g*9;
    const unsigned short* img = xproj + (size_t)n*(HH*WWD*CC) + g*16 + c4*4;
    float4 acc = {0.f, 0.f, 0.f, 0.f};
    #pragma unroll
    for (int p = 0; p < 9; ++p) {
        float ox = op[p*2+0], oy = op[p*2+1];
        float xs = (float)(w + p/3) + ox;   // padded-image coords
        float ys = (float)(h + p%3) + oy;
        float x0f = floorf(xs), y0f = floorf(ys);
        float lx = xs - x0f, ly = ys - y0f;
        int x0 = (int)x0f, y0 = (int)y0f;
        float4 s = {0.f, 0.f, 0.f, 0.f};
        tap4b(img, y0,   x0,   (1.f-lx)*(1.f-ly), s);
        tap4b(img, y0,   x0+1, lx*(1.f-ly),       s);
        tap4b(img, y0+1, x0,   (1.f-lx)*ly,       s);
        tap4b(img, y0+1, x0+1, lx*ly,             s);
        float m = mp[p];
        acc.x += m*s.x; acc.y += m*s.y; acc.z += m*s.z; acc.w += m*s.w;
    }
    ushort4 o;
    o.x = f2bf(acc.x); o.y = f2bf(acc.y); o.z = f2bf(acc.z); o.w = f2bf(acc.w);
    *reinterpret_cast<ushort4*>(&dcn[(size_t)pix*CC + g*16 + c4*4]) = o;
}

extern "C" void kernel_launch(void* const* d_in, const int* in_sizes, int n_in,
                              void* d_out, int out_size, void* d_ws, size_t ws_size,
                              hipStream_t stream)
{
    const float* x    = (const float*)d_in[0];
    const float* n1g  = (const float*)d_in[1];
    const float* n1b  = (const float*)d_in[2];
    const float* n2g  = (const float*)d_in[3];
    const float* n2b  = (const float*)d_in[4];
    const float* g1   = (const float*)d_in[5];
    const float* g2   = (const float*)d_in[6];
    const float* dww  = (const float*)d_in[7];
    const float* dwb  = (const float*)d_in[8];
    const float* dlng = (const float*)d_in[9];
    const float* dlnb = (const float*)d_in[10];
    const float* offw = (const float*)d_in[11];
    const float* offb = (const float*)d_in[12];
    const float* mskw = (const float*)d_in[13];
    const float* mskb = (const float*)d_in[14];
    const float* inw  = (const float*)d_in[15];
    const float* inb  = (const float*)d_in[16];
    const float* outw = (const float*)d_in[17];
    const float* outb = (const float*)d_in[18];
    const float* f1w  = (const float*)d_in[19];
    const float* f1b  = (const float*)d_in[20];
    const float* f2w  = (const float*)d_in[21];
    const float* f2b  = (const float*)d_in[22];
    float* out = (float*)d_out;

    char* base = (char*)d_ws;
    // arena (bytes)
    unsigned short* xl_bf    = (unsigned short*)(base + 0);          // 12,845,056 B
    unsigned short* xproj_bf = (unsigned short*)(base + 12845056);   // 12,845,056 B
    float*          xres     = (float*)(base + 12845056 + 12845056); // 25,690,112 B
    unsigned short* x1_bf    = (unsigned short*)(base + 51380224);   // 12,845,056 B
    float*          offs     = (float*)(base + 64225280);            // 28,901,376 B
    float*          msk      = (float*)(base + 93126656);            // 14,450,688 B
    unsigned short* dcn_bf   = xl_bf;                                 // reuse region A
    unsigned short* y2_bf    = x1_bf;                                 // reuse region C
    unsigned short* h1       = (unsigned short*)(base + 64225280);   // 51,380,224 B (over offs+msk)
    unsigned short* btb      = (unsigned short*)(base + 115605504);  // 1,638,400 B
    unsigned short* bt_in  = btb + 0;
    unsigned short* bt_off = btb + 65536;
    unsigned short* bt_msk = btb + 163840;
    unsigned short* bt_out = btb + 229376;
    unsigned short* bt_fc1 = btb + 294912;
    unsigned short* bt_fc2 = btb + 557056;

    // 0. weight transposes (fp32 -> bf16, N-major, padded to x128 rows)
    wtrans_kernel<<<256,  256, 0, stream>>>(inw,  bt_in,  256, 256,  256);
    wtrans_kernel<<<384,  256, 0, stream>>>(offw, bt_off, 256, 288,  384);
    wtrans_kernel<<<256,  256, 0, stream>>>(mskw, bt_msk, 256, 144,  256);
    wtrans_kernel<<<256,  256, 0, stream>>>(outw, bt_out, 256, 256,  256);
    wtrans_kernel<<<1024, 256, 0, stream>>>(f1w,  bt_fc1, 256, 1024, 1024);
    wtrans_kernel<<<1024, 256, 0, stream>>>(f2w,  bt_fc2, 1024, 256, 256);

    // 1. LN1 -> xl (bf16)
    ln_bf_kernel<<<PIX/4, 256, 0, stream>>>(x, n1g, n1b, xl_bf);
    // 2. in_proj -> xproj (bf16)
    gemm_bf16<3><<<dim3(2,196), 256, 0, stream>>>(xl_bf, bt_in, inb, nullptr,
        xproj_bf, PIX, 256, 256, nullptr, nullptr);
    // 3. depthwise conv + LN + GELU -> x1 (bf16)
    dwconv_ln_gelu_kernel<<<PIX/4, 256, 0, stream>>>(xl_bf, dww, dwb, dlng, dlnb, x1_bf);
    // 4. offset & mask GEMMs (fp32 out)
    gemm_bf16<0><<<dim3(3,196), 256, 0, stream>>>(x1_bf, bt_off, offb, offs,
        nullptr, PIX, 288, 256, nullptr, nullptr);
    gemm_bf16<0><<<dim3(2,196), 256, 0, stream>>>(x1_bf, bt_msk, mskb, msk,
        nullptr, PIX, 144, 256, nullptr, nullptr);
    // 5. softmax over P
    softmax9_kernel<<<(PIX*16)/256, 256, 0, stream>>>(msk, PIX*16);
    // 6. deformable sampling -> dcn (bf16, reuses xl region)
    dcn_sample_kernel<<<PIX/4, 256, 0, stream>>>(xproj_bf, offs, msk, dcn_bf);
    // 7. out_proj + residual: xres = x + gamma1*(dcn@out_w + out_b)  (fp32)
    gemm_bf16<2><<<dim3(2,196), 256, 0, stream>>>(dcn_bf, bt_out, outb, xres,
        nullptr, PIX, 256, 256, x, g1);
    // 8. LN2 -> y2 (bf16, reuses x1 region)
    ln_bf_kernel<<<PIX/4, 256, 0, stream>>>(xres, n2g, n2b, y2_bf);
    // 9. fc1 + gelu -> h1 (bf16)
    gemm_bf16<1><<<dim3(8,196), 256, 0, stream>>>(y2_bf, bt_fc1, f1b, nullptr,
        h1, PIX, 1024, 256, nullptr, nullptr);
    // 10. fc2 + residual -> out (fp32)
    gemm_bf16<2><<<dim3(2,196), 256, 0, stream>>>(h1, bt_fc2, f2b, out,
        nullptr, PIX, 256, 1024, xres, g2);
}